// Round 2
// baseline (1628.765 us; speedup 1.0000x reference)
//
#include <hip/hip_runtime.h>
#include <hip/hip_bf16.h>

typedef __attribute__((ext_vector_type(8))) short bf16x8;
typedef __attribute__((ext_vector_type(4))) float f32x4;

static __device__ __forceinline__ unsigned short f2bf(float f) {
    union { float f; unsigned u; } v; v.f = f;
    unsigned r = v.u + 0x7fffu + ((v.u >> 16) & 1u);
    return (unsigned short)(r >> 16);
}

#define GLOAD16(g, l) __builtin_amdgcn_global_load_lds( \
    (const __attribute__((address_space(1))) void*)(g), \
    (__attribute__((address_space(3))) void*)(l), 16, 0, 0)

// ---------------------------------------------------------------------------
// Weight conversion: fp32 -> bf16, tiled [nb][ks] (256n x 64k per tile) with
// bank swizzle baked in: within tile, element (nl,kk) sits at short index
//   nl*64 + (kk ^ ((nl&7)<<3))
// so GEMM kernels can global_load_lds the tile linearly.
// ---------------------------------------------------------------------------
__global__ __launch_bounds__(256) void conv_weights(
    const float* __restrict__ Wvv, const float* __restrict__ Wvc,
    const float* __restrict__ bW1, const float* __restrict__ uW1,
    unsigned short* __restrict__ WcT, unsigned short* __restrict__ bW1T,
    unsigned short* __restrict__ uW1T)
{
    int idx = blockIdx.x * 256 + threadIdx.x;
    if (idx < 131072) {                       // WcT: K=512 (vv then vc), N=256
        int n = idx & 255, k = idx >> 8;
        float s = (k < 256) ? Wvv[k * 256 + n] : Wvc[(k - 256) * 256 + n];
        int ks = k >> 6, kk = k & 63;
        WcT[ks * 16384 + n * 64 + (kk ^ ((n & 7) << 3))] = f2bf(s);
    } else if (idx < 131072 + 262144) {       // bW1T: K=512, N=512
        int t = idx - 131072;
        int n = t & 511, k = t >> 9;
        int nb = n >> 8, nl = n & 255, ks = k >> 6, kk = k & 63;
        bW1T[(nb * 8 + ks) * 16384 + nl * 64 + (kk ^ ((nl & 7) << 3))] = f2bf(bW1[k * 512 + n]);
    } else if (idx < 131072 + 262144 + 131072) { // uW1T: K=256, N=512
        int t = idx - 393216;
        int n = t & 511, k = t >> 9;
        int nb = n >> 8, nl = n & 255, ks = k >> 6, kk = k & 63;
        uW1T[(nb * 4 + ks) * 16384 + nl * 64 + (kk ^ ((nl & 7) << 3))] = f2bf(uW1[k * 512 + n]);
    }
}

// init output with biases (bond/uni kernels atomicAdd partials on top)
__global__ __launch_bounds__(256) void init_out(
    float* __restrict__ out, const float* __restrict__ bb2,
    const float* __restrict__ ub2, int NB5, int NA)
{
    int i = blockIdx.x * 256 + threadIdx.x;
    if (i < NB5) out[i] = bb2[i - (i / 5) * 5];
    else if (i < NB5 + NA) out[i] = ub2[0];
}

// ---------------------------------------------------------------------------
// ha = relu(ha_prev @ W_vv + c_atom @ W_vc); ha[0]=0
// BM=128, N=256, K=512 (8 K-steps of 64). 8 waves (2x4), 64x64 each.
// A: fp32 -> bf16 reg-staged into swizzled LDS. B: global_load_lds (pre-swz).
// Epilogue: bf16 store of ha + fp32 atomic hm accumulation.
// ---------------------------------------------------------------------------
__global__ __launch_bounds__(512, 4) void ha_kernel(
    const float* __restrict__ ha_prev, const float* __restrict__ c_atom,
    const unsigned short* __restrict__ WcT, const int* __restrict__ mol_id,
    unsigned short* __restrict__ haB, float* __restrict__ hm, int NA)
{
    __shared__ __align__(16) unsigned short As[128 * 64];
    __shared__ __align__(16) unsigned short Bs[256 * 64];

    const int tid = threadIdx.x;
    const int wv = tid >> 6, lane = tid & 63;
    const int wr = wv >> 2, wc = wv & 3;
    const int c15 = lane & 15, kq = lane >> 4;
    const int xm3 = (c15 & 7) << 3;
    const int m0 = blockIdx.x * 128;

    f32x4 acc[4][4];
#pragma unroll
    for (int m = 0; m < 4; ++m)
#pragma unroll
        for (int n = 0; n < 4; ++n) acc[m][n] = (f32x4){0.f, 0.f, 0.f, 0.f};

    for (int ks = 0; ks < 8; ++ks) {
        __syncthreads();
        // B stage: tile ks of WcT, linear DMA (swizzle pre-baked)
        const unsigned short* bt = WcT + ks * 16384;
#pragma unroll
        for (int i = 0; i < 4; ++i) {
            GLOAD16(bt + (size_t)(i * 512 + wv * 64 + lane) * 8,
                    Bs + (i * 512 + wv * 64) * 8);
        }
        // A stage: fp32 load + cvt + swizzled ds_write
        const float* src = (ks < 4) ? ha_prev : c_atom;
        const int kb = (ks & 3) * 64;
#pragma unroll
        for (int i = 0; i < 2; ++i) {
            int c = i * 512 + tid;
            int r = c >> 3, hc = c & 7;
            int row = m0 + r; if (row >= NA) row = NA - 1;
            const float* s = src + (size_t)row * 256 + kb + hc * 8;
            f32x4 v0 = *(const f32x4*)s;
            f32x4 v1 = *(const f32x4*)(s + 4);
            bf16x8 pk;
            pk[0] = (short)f2bf(v0[0]); pk[1] = (short)f2bf(v0[1]);
            pk[2] = (short)f2bf(v0[2]); pk[3] = (short)f2bf(v0[3]);
            pk[4] = (short)f2bf(v1[0]); pk[5] = (short)f2bf(v1[1]);
            pk[6] = (short)f2bf(v1[2]); pk[7] = (short)f2bf(v1[3]);
            *(bf16x8*)&As[r * 64 + ((hc * 8) ^ ((r & 7) << 3))] = pk;
        }
        __syncthreads();
#pragma unroll
        for (int kk = 0; kk < 2; ++kk) {
            bf16x8 aF[4], bF[4];
#pragma unroll
            for (int m = 0; m < 4; ++m)
                aF[m] = *(const bf16x8*)&As[(wr * 64 + m * 16 + c15) * 64 + ((kk * 32 + kq * 8) ^ xm3)];
#pragma unroll
            for (int n = 0; n < 4; ++n)
                bF[n] = *(const bf16x8*)&Bs[(wc * 64 + n * 16 + c15) * 64 + ((kk * 32 + kq * 8) ^ xm3)];
#pragma unroll
            for (int m = 0; m < 4; ++m)
#pragma unroll
                for (int n = 0; n < 4; ++n)
                    acc[m][n] = __builtin_amdgcn_mfma_f32_16x16x32_bf16(aF[m], bF[n], acc[m][n], 0, 0, 0);
        }
    }

#pragma unroll
    for (int m = 0; m < 4; ++m) {
#pragma unroll
        for (int reg = 0; reg < 4; ++reg) {
            int row = m0 + wr * 64 + m * 16 + kq * 4 + reg;
            if (row >= NA) continue;
            bool z = (row == 0);
            int mol = z ? 0 : mol_id[row];
#pragma unroll
            for (int n = 0; n < 4; ++n) {
                int col = wc * 64 + n * 16 + c15;
                float v = fmaxf(acc[m][n][reg], 0.f);
                if (z) v = 0.f;
                haB[(size_t)row * 256 + col] = f2bf(v);
                if (!z) atomicAdd(&hm[mol * 256 + col], v);
            }
        }
    }
}

// ---------------------------------------------------------------------------
// bond partial: hidden = relu([ha[b0]|ha[b1]] @ W1[:,nb*256:+256] + b1),
// atomicAdd(hidden @ W2) into outB. BM=128 bonds, BN=256, K=512 (8 steps).
// A gathered via global_load_lds with pre-swizzled per-lane global addrs.
// ---------------------------------------------------------------------------
__global__ __launch_bounds__(512, 4) void bond_kernel(
    const unsigned short* __restrict__ haB, const int* __restrict__ bidx,
    const unsigned short* __restrict__ bW1T, const float* __restrict__ b1,
    const float* __restrict__ W2, float* __restrict__ outB, int NB)
{
    __shared__ __align__(16) unsigned short As[128 * 64];
    __shared__ __align__(16) unsigned short Bs[256 * 64];

    const int tid = threadIdx.x;
    const int wv = tid >> 6, lane = tid & 63;
    const int wr = wv >> 2, wc = wv & 3;
    const int c15 = lane & 15, kq = lane >> 4;
    const int xm3 = (c15 & 7) << 3;
    const int b0 = blockIdx.x * 128;
    const int nb = blockIdx.y;

    // per-lane gather setup: this lane stages rows rowA and rowA+64
    const int rowA = wv * 8 + (lane >> 3);
    const int srcoff = ((lane & 7) << 3) ^ ((lane >> 3) << 3);
    int gr0 = b0 + rowA; if (gr0 >= NB) gr0 = 0;
    int gr1 = gr0 + 64;  if (gr1 >= NB) gr1 = 0;
    const int e00 = bidx[gr0 * 2], e01 = bidx[gr0 * 2 + 1];
    const int e10 = bidx[gr1 * 2], e11 = bidx[gr1 * 2 + 1];

    f32x4 acc[4][4];
#pragma unroll
    for (int m = 0; m < 4; ++m)
#pragma unroll
        for (int n = 0; n < 4; ++n) acc[m][n] = (f32x4){0.f, 0.f, 0.f, 0.f};

    for (int ks = 0; ks < 8; ++ks) {
        __syncthreads();
        const unsigned short* bt = bW1T + (size_t)(nb * 8 + ks) * 16384;
#pragma unroll
        for (int i = 0; i < 4; ++i) {
            GLOAD16(bt + (size_t)(i * 512 + wv * 64 + lane) * 8,
                    Bs + (i * 512 + wv * 64) * 8);
        }
        const int kc = (ks & 3) * 64 + srcoff;
        const unsigned short* g0 = haB + (size_t)((ks >> 2) ? e01 : e00) * 256 + kc;
        const unsigned short* g1 = haB + (size_t)((ks >> 2) ? e11 : e10) * 256 + kc;
        GLOAD16(g0, As + (wv * 64) * 8);
        GLOAD16(g1, As + (512 + wv * 64) * 8);
        __syncthreads();
#pragma unroll
        for (int kk = 0; kk < 2; ++kk) {
            bf16x8 aF[4], bF[4];
#pragma unroll
            for (int m = 0; m < 4; ++m)
                aF[m] = *(const bf16x8*)&As[(wr * 64 + m * 16 + c15) * 64 + ((kk * 32 + kq * 8) ^ xm3)];
#pragma unroll
            for (int n = 0; n < 4; ++n)
                bF[n] = *(const bf16x8*)&Bs[(wc * 64 + n * 16 + c15) * 64 + ((kk * 32 + kq * 8) ^ xm3)];
#pragma unroll
            for (int m = 0; m < 4; ++m)
#pragma unroll
                for (int n = 0; n < 4; ++n)
                    acc[m][n] = __builtin_amdgcn_mfma_f32_16x16x32_bf16(aF[m], bF[n], acc[m][n], 0, 0, 0);
        }
    }

    // fused layer 2 over this block's 256 hidden cols
    float b1c[4], w2c[4][5];
#pragma unroll
    for (int n = 0; n < 4; ++n) {
        int col = nb * 256 + wc * 64 + n * 16 + c15;
        b1c[n] = b1[col];
#pragma unroll
        for (int j = 0; j < 5; ++j) w2c[n][j] = W2[col * 5 + j];
    }
#pragma unroll
    for (int m = 0; m < 4; ++m) {
#pragma unroll
        for (int reg = 0; reg < 4; ++reg) {
            float s[5] = {0.f, 0.f, 0.f, 0.f, 0.f};
#pragma unroll
            for (int n = 0; n < 4; ++n) {
                float p = fmaxf(acc[m][n][reg] + b1c[n], 0.f);
#pragma unroll
                for (int j = 0; j < 5; ++j) s[j] += p * w2c[n][j];
            }
#pragma unroll
            for (int off = 1; off < 16; off <<= 1)
#pragma unroll
                for (int j = 0; j < 5; ++j) s[j] += __shfl_xor(s[j], off);
            if (c15 == 0) {
                int row = b0 + wr * 64 + m * 16 + kq * 4 + reg;
                if (row < NB)
#pragma unroll
                    for (int j = 0; j < 5; ++j) atomicAdd(&outB[(size_t)row * 5 + j], s[j]);
            }
        }
    }
}

// ---------------------------------------------------------------------------
// uni partial: same template, A = haB rows (linear), K=256 (4 steps), out dim 1
// ---------------------------------------------------------------------------
__global__ __launch_bounds__(512, 4) void uni_kernel(
    const unsigned short* __restrict__ haB, const unsigned short* __restrict__ uW1T,
    const float* __restrict__ b1, const float* __restrict__ W2,
    float* __restrict__ outU, int NA)
{
    __shared__ __align__(16) unsigned short As[128 * 64];
    __shared__ __align__(16) unsigned short Bs[256 * 64];

    const int tid = threadIdx.x;
    const int wv = tid >> 6, lane = tid & 63;
    const int wr = wv >> 2, wc = wv & 3;
    const int c15 = lane & 15, kq = lane >> 4;
    const int xm3 = (c15 & 7) << 3;
    const int a0 = blockIdx.x * 128;
    const int nb = blockIdx.y;

    const int rowA = wv * 8 + (lane >> 3);
    const int srcoff = ((lane & 7) << 3) ^ ((lane >> 3) << 3);
    int r0 = a0 + rowA;      if (r0 >= NA) r0 = NA - 1;
    int r1 = a0 + rowA + 64; if (r1 >= NA) r1 = NA - 1;

    f32x4 acc[4][4];
#pragma unroll
    for (int m = 0; m < 4; ++m)
#pragma unroll
        for (int n = 0; n < 4; ++n) acc[m][n] = (f32x4){0.f, 0.f, 0.f, 0.f};

    for (int ks = 0; ks < 4; ++ks) {
        __syncthreads();
        const unsigned short* bt = uW1T + (size_t)(nb * 4 + ks) * 16384;
#pragma unroll
        for (int i = 0; i < 4; ++i) {
            GLOAD16(bt + (size_t)(i * 512 + wv * 64 + lane) * 8,
                    Bs + (i * 512 + wv * 64) * 8);
        }
        const int kc = ks * 64 + srcoff;
        GLOAD16(haB + (size_t)r0 * 256 + kc, As + (wv * 64) * 8);
        GLOAD16(haB + (size_t)r1 * 256 + kc, As + (512 + wv * 64) * 8);
        __syncthreads();
#pragma unroll
        for (int kk = 0; kk < 2; ++kk) {
            bf16x8 aF[4], bF[4];
#pragma unroll
            for (int m = 0; m < 4; ++m)
                aF[m] = *(const bf16x8*)&As[(wr * 64 + m * 16 + c15) * 64 + ((kk * 32 + kq * 8) ^ xm3)];
#pragma unroll
            for (int n = 0; n < 4; ++n)
                bF[n] = *(const bf16x8*)&Bs[(wc * 64 + n * 16 + c15) * 64 + ((kk * 32 + kq * 8) ^ xm3)];
#pragma unroll
            for (int m = 0; m < 4; ++m)
#pragma unroll
                for (int n = 0; n < 4; ++n)
                    acc[m][n] = __builtin_amdgcn_mfma_f32_16x16x32_bf16(aF[m], bF[n], acc[m][n], 0, 0, 0);
        }
    }

    float b1c[4], w2c[4];
#pragma unroll
    for (int n = 0; n < 4; ++n) {
        int col = nb * 256 + wc * 64 + n * 16 + c15;
        b1c[n] = b1[col];
        w2c[n] = W2[col];
    }
#pragma unroll
    for (int m = 0; m < 4; ++m) {
#pragma unroll
        for (int reg = 0; reg < 4; ++reg) {
            float s = 0.f;
#pragma unroll
            for (int n = 0; n < 4; ++n)
                s += fmaxf(acc[m][n][reg] + b1c[n], 0.f) * w2c[n];
#pragma unroll
            for (int off = 1; off < 16; off <<= 1) s += __shfl_xor(s, off);
            if (c15 == 0) {
                int row = a0 + wr * 64 + m * 16 + kq * 4 + reg;
                if (row < NA) atomicAdd(&outU[row], s);
            }
        }
    }
}

// ---------------------------------------------------------------------------
// done_logits: 4 molecules per block (W1 streamed once per 4 mols), fp32
// ---------------------------------------------------------------------------
__global__ __launch_bounds__(256) void done_kernel(
    const float* __restrict__ hm, const float* __restrict__ W1,
    const float* __restrict__ b1, const float* __restrict__ W2,
    const float* __restrict__ b2, float* __restrict__ outD, int NM)
{
    __shared__ float rsh[4][256];
    __shared__ float red[4][4];
    const int tid = threadIdx.x;
    const int wv = tid >> 6, lane = tid & 63;
    const int mol0 = blockIdx.x * 4;
#pragma unroll
    for (int q = 0; q < 4; ++q)
        rsh[q][tid] = (mol0 + q < NM) ? hm[(size_t)(mol0 + q) * 256 + tid] : 0.f;
    __syncthreads();
    float h[4][2];
#pragma unroll
    for (int q = 0; q < 4; ++q) { h[q][0] = 0.f; h[q][1] = 0.f; }
    for (int k = 0; k < 256; ++k) {
        float w0 = W1[k * 512 + tid];
        float w1 = W1[k * 512 + tid + 256];
#pragma unroll
        for (int q = 0; q < 4; ++q) {
            h[q][0] += rsh[q][k] * w0;
            h[q][1] += rsh[q][k] * w1;
        }
    }
    float bb0 = b1[tid], bb1v = b1[tid + 256];
    float ww0 = W2[tid], ww1 = W2[tid + 256];
#pragma unroll
    for (int q = 0; q < 4; ++q) {
        float p = fmaxf(h[q][0] + bb0, 0.f) * ww0 + fmaxf(h[q][1] + bb1v, 0.f) * ww1;
#pragma unroll
        for (int off = 1; off < 64; off <<= 1) p += __shfl_xor(p, off);
        if (lane == 0) red[q][wv] = p;
    }
    __syncthreads();
    if (tid < 4 && mol0 + tid < NM)
        outD[mol0 + tid] = red[tid][0] + red[tid][1] + red[tid][2] + red[tid][3] + b2[0];
}

// ---------------------------------------------------------------------------
extern "C" void kernel_launch(void* const* d_in, const int* in_sizes, int n_in,
                              void* d_out, int out_size, void* d_ws, size_t ws_size,
                              hipStream_t stream)
{
    const float* c_atom  = (const float*)d_in[0];
    const float* ha_prev = (const float*)d_in[1];
    const float* W_vv    = (const float*)d_in[2];
    const float* W_vc    = (const float*)d_in[3];
    const float* bW1     = (const float*)d_in[4];
    const float* bb1     = (const float*)d_in[5];
    const float* bW2     = (const float*)d_in[6];
    const float* bb2     = (const float*)d_in[7];
    const float* uW1     = (const float*)d_in[8];
    const float* ub1     = (const float*)d_in[9];
    const float* uW2     = (const float*)d_in[10];
    const float* ub2     = (const float*)d_in[11];
    const float* dW1     = (const float*)d_in[12];
    const float* db1     = (const float*)d_in[13];
    const float* dW2     = (const float*)d_in[14];
    const float* db2     = (const float*)d_in[15];
    const int* mol_id    = (const int*)d_in[16];
    const int* bidx      = (const int*)d_in[17];

    const int H = 256, BS = 5;
    const int NA = in_sizes[0] / H;
    const int NB = in_sizes[17] / 2;
    const int NM = out_size - NB * BS - NA;

    float* out  = (float*)d_out;
    float* outB = out;
    float* outU = out + (size_t)NB * BS;
    float* outD = outU + NA;

    char* ws = (char*)d_ws;
    size_t off = 0;
    unsigned short* haB = (unsigned short*)(ws + off);
    off += (size_t)NA * H * 2;            off = (off + 255) & ~(size_t)255;
    float* hm = (float*)(ws + off);
    off += (size_t)NM * H * 4;            off = (off + 255) & ~(size_t)255;
    unsigned short* WcT = (unsigned short*)(ws + off);
    off += (size_t)131072 * 2;            off = (off + 255) & ~(size_t)255;
    unsigned short* bW1T = (unsigned short*)(ws + off);
    off += (size_t)262144 * 2;            off = (off + 255) & ~(size_t)255;
    unsigned short* uW1T = (unsigned short*)(ws + off);

    hipMemsetAsync(hm, 0, (size_t)NM * H * 4, stream);
    conv_weights<<<2048, 256, 0, stream>>>(W_vv, W_vc, bW1, uW1, WcT, bW1T, uW1T);
    init_out<<<(NB * BS + NA + 255) / 256, 256, 0, stream>>>(out, bb2, ub2, NB * BS, NA);
    ha_kernel<<<(NA + 127) / 128, 512, 0, stream>>>(ha_prev, c_atom, WcT, mol_id, haB, hm, NA);
    bond_kernel<<<dim3((NB + 127) / 128, 2), 512, 0, stream>>>(haB, bidx, bW1T, bb1, bW2, outB, NB);
    uni_kernel<<<dim3((NA + 127) / 128, 2), 512, 0, stream>>>(haB, uW1T, ub1, uW2, outU, NA);
    done_kernel<<<(NM + 3) / 4, 256, 0, stream>>>(hm, dW1, db1, dW2, db2, outD, NM);
}

// Round 3
// 800.381 us; speedup vs baseline: 2.0350x; 2.0350x over previous
//
#include <hip/hip_runtime.h>
#include <hip/hip_bf16.h>

typedef __attribute__((ext_vector_type(8))) short bf16x8;
typedef __attribute__((ext_vector_type(4))) float f32x4;

static __device__ __forceinline__ unsigned short f2bf(float f) {
    union { float f; unsigned u; } v; v.f = f;
    unsigned r = v.u + 0x7fffu + ((v.u >> 16) & 1u);
    return (unsigned short)(r >> 16);
}

#define GLOAD16(g, l) __builtin_amdgcn_global_load_lds( \
    (const __attribute__((address_space(1))) void*)(g), \
    (__attribute__((address_space(3))) void*)(l), 16, 0, 0)

// ---------------------------------------------------------------------------
// Weight conversion: fp32 -> bf16, K-step tiles with bank swizzle baked in.
// WcT : [ks 0..7][n 0..255][kk 0..63]  (K=512: vv rows then vc rows), ha layout
// bW1T: [ks 0..7][n 0..511][kk 0..63]  full-N tiles (64 KB each)
// uW1T: [ks 0..3][n 0..511][kk 0..63]
// element (n,kk) at short index n*64 + (kk ^ ((n&7)<<3))
// ---------------------------------------------------------------------------
__global__ __launch_bounds__(256) void conv_weights(
    const float* __restrict__ Wvv, const float* __restrict__ Wvc,
    const float* __restrict__ bW1, const float* __restrict__ uW1,
    unsigned short* __restrict__ WcT, unsigned short* __restrict__ bW1T,
    unsigned short* __restrict__ uW1T)
{
    int idx = blockIdx.x * 256 + threadIdx.x;
    if (idx < 131072) {                       // WcT: K=512 (vv then vc), N=256
        int n = idx & 255, k = idx >> 8;
        float s = (k < 256) ? Wvv[k * 256 + n] : Wvc[(k - 256) * 256 + n];
        int ks = k >> 6, kk = k & 63;
        WcT[ks * 16384 + n * 64 + (kk ^ ((n & 7) << 3))] = f2bf(s);
    } else if (idx < 131072 + 262144) {       // bW1T: K=512, N=512
        int t = idx - 131072;
        int n = t & 511, k = t >> 9;
        int ks = k >> 6, kk = k & 63;
        bW1T[ks * 32768 + n * 64 + (kk ^ ((n & 7) << 3))] = f2bf(bW1[k * 512 + n]);
    } else if (idx < 131072 + 262144 + 131072) { // uW1T: K=256, N=512
        int t = idx - 393216;
        int n = t & 511, k = t >> 9;
        int ks = k >> 6, kk = k & 63;
        uW1T[ks * 32768 + n * 64 + (kk ^ ((n & 7) << 3))] = f2bf(uW1[k * 512 + n]);
    }
}

// ---------------------------------------------------------------------------
// ha = relu(ha_prev @ W_vv + c_atom @ W_vc); ha[0]=0
// BM=128, N=256, K=512 (8 K-steps of 64). 8 waves (2x4), 64x64 each.
// A: fp32 -> bf16 reg-staged into swizzled LDS. B: global_load_lds (pre-swz).
// Epilogue: bf16 store of ha + fp32 atomic hm accumulation.
// ---------------------------------------------------------------------------
__global__ __launch_bounds__(512, 4) void ha_kernel(
    const float* __restrict__ ha_prev, const float* __restrict__ c_atom,
    const unsigned short* __restrict__ WcT, const int* __restrict__ mol_id,
    unsigned short* __restrict__ haB, float* __restrict__ hm, int NA)
{
    __shared__ __align__(16) unsigned short As[128 * 64];
    __shared__ __align__(16) unsigned short Bs[256 * 64];

    const int tid = threadIdx.x;
    const int wv = tid >> 6, lane = tid & 63;
    const int wr = wv >> 2, wc = wv & 3;
    const int c15 = lane & 15, kq = lane >> 4;
    const int xm3 = (c15 & 7) << 3;
    const int m0 = blockIdx.x * 128;

    f32x4 acc[4][4];
#pragma unroll
    for (int m = 0; m < 4; ++m)
#pragma unroll
        for (int n = 0; n < 4; ++n) acc[m][n] = (f32x4){0.f, 0.f, 0.f, 0.f};

    for (int ks = 0; ks < 8; ++ks) {
        __syncthreads();
        const unsigned short* bt = WcT + ks * 16384;
#pragma unroll
        for (int i = 0; i < 4; ++i) {
            GLOAD16(bt + (size_t)(i * 512 + wv * 64 + lane) * 8,
                    Bs + (i * 512 + wv * 64) * 8);
        }
        const float* src = (ks < 4) ? ha_prev : c_atom;
        const int kb = (ks & 3) * 64;
#pragma unroll
        for (int i = 0; i < 2; ++i) {
            int c = i * 512 + tid;
            int r = c >> 3, hc = c & 7;
            int row = m0 + r; if (row >= NA) row = NA - 1;
            const float* s = src + (size_t)row * 256 + kb + hc * 8;
            f32x4 v0 = *(const f32x4*)s;
            f32x4 v1 = *(const f32x4*)(s + 4);
            bf16x8 pk;
            pk[0] = (short)f2bf(v0[0]); pk[1] = (short)f2bf(v0[1]);
            pk[2] = (short)f2bf(v0[2]); pk[3] = (short)f2bf(v0[3]);
            pk[4] = (short)f2bf(v1[0]); pk[5] = (short)f2bf(v1[1]);
            pk[6] = (short)f2bf(v1[2]); pk[7] = (short)f2bf(v1[3]);
            *(bf16x8*)&As[r * 64 + ((hc * 8) ^ ((r & 7) << 3))] = pk;
        }
        __syncthreads();
#pragma unroll
        for (int kk = 0; kk < 2; ++kk) {
            bf16x8 aF[4], bF[4];
#pragma unroll
            for (int m = 0; m < 4; ++m)
                aF[m] = *(const bf16x8*)&As[(wr * 64 + m * 16 + c15) * 64 + ((kk * 32 + kq * 8) ^ xm3)];
#pragma unroll
            for (int n = 0; n < 4; ++n)
                bF[n] = *(const bf16x8*)&Bs[(wc * 64 + n * 16 + c15) * 64 + ((kk * 32 + kq * 8) ^ xm3)];
#pragma unroll
            for (int m = 0; m < 4; ++m)
#pragma unroll
                for (int n = 0; n < 4; ++n)
                    acc[m][n] = __builtin_amdgcn_mfma_f32_16x16x32_bf16(aF[m], bF[n], acc[m][n], 0, 0, 0);
        }
    }

#pragma unroll
    for (int m = 0; m < 4; ++m) {
#pragma unroll
        for (int reg = 0; reg < 4; ++reg) {
            int row = m0 + wr * 64 + m * 16 + kq * 4 + reg;
            if (row >= NA) continue;
            bool z = (row == 0);
            int mol = z ? 0 : mol_id[row];
#pragma unroll
            for (int n = 0; n < 4; ++n) {
                int col = wc * 64 + n * 16 + c15;
                float v = fmaxf(acc[m][n][reg], 0.f);
                if (z) v = 0.f;
                haB[(size_t)row * 256 + col] = f2bf(v);
                if (!z) atomicAdd(&hm[mol * 256 + col], v);
            }
        }
    }
}

// ---------------------------------------------------------------------------
// bond: logits = relu([ha[b0]|ha[b1]] @ W1 + b1) @ W2 + b2, fully fused.
// BM=64 bonds, N=512 (full), K=512 (8 steps of 64). 8 waves, 64 cols each.
// A gathered via GLOAD16: each 8-lane group covers one contiguous 128B row
// slice (XOR-permuted chunks -> swizzled LDS via pre-swizzled global addr).
// Output block-local: LDS combine across waves, direct store (no g-atomics).
// ---------------------------------------------------------------------------
__global__ __launch_bounds__(512, 4) void bond_kernel(
    const unsigned short* __restrict__ haB, const int* __restrict__ bidx,
    const unsigned short* __restrict__ bW1T, const float* __restrict__ b1,
    const float* __restrict__ W2, const float* __restrict__ b2,
    float* __restrict__ outB, int NB)
{
    __shared__ __align__(16) unsigned short As[64 * 64];    // 8 KB
    __shared__ __align__(16) unsigned short Bs[512 * 64];   // 64 KB
    __shared__ float obuf[64][5];

    const int tid = threadIdx.x;
    const int wv = tid >> 6, lane = tid & 63;
    const int c15 = lane & 15, kq = lane >> 4;
    const int xm3 = (c15 & 7) << 3;
    const int b0 = blockIdx.x * 64;

    if (tid < 320) ((float*)obuf)[tid] = 0.f;

    // A staging assignment: wave wv stages rows wv*8..wv*8+7; lane group
    // g=lane>>3 owns row wv*8+g; chunk c=lane&7 reads swizzled slot (c^g)*8
    const int rA = wv * 8 + (lane >> 3);
    const int srcswz = ((lane & 7) ^ ((lane >> 3) & 7)) << 3;
    int gb = b0 + rA; if (gb >= NB) gb = 0;
    const int e0 = bidx[gb * 2], e1 = bidx[gb * 2 + 1];

    f32x4 acc[4][4];
#pragma unroll
    for (int m = 0; m < 4; ++m)
#pragma unroll
        for (int n = 0; n < 4; ++n) acc[m][n] = (f32x4){0.f, 0.f, 0.f, 0.f};

    for (int ks = 0; ks < 8; ++ks) {
        __syncthreads();
        const unsigned short* bt = bW1T + ks * 32768;
#pragma unroll
        for (int j = 0; j < 8; ++j) {
            GLOAD16(bt + (size_t)((j * 8 + wv) * 512) + lane * 8,
                    Bs + (j * 8 + wv) * 512);
        }
        const unsigned short* ga =
            haB + (size_t)((ks < 4) ? e0 : e1) * 256 + (ks & 3) * 64 + srcswz;
        GLOAD16(ga, As + wv * 512);
        __syncthreads();
#pragma unroll
        for (int kk = 0; kk < 2; ++kk) {
            bf16x8 aF[4], bF[4];
#pragma unroll
            for (int m = 0; m < 4; ++m)
                aF[m] = *(const bf16x8*)&As[(m * 16 + c15) * 64 + ((kk * 32 + kq * 8) ^ xm3)];
#pragma unroll
            for (int n = 0; n < 4; ++n)
                bF[n] = *(const bf16x8*)&Bs[(wv * 64 + n * 16 + c15) * 64 + ((kk * 32 + kq * 8) ^ xm3)];
#pragma unroll
            for (int m = 0; m < 4; ++m)
#pragma unroll
                for (int n = 0; n < 4; ++n)
                    acc[m][n] = __builtin_amdgcn_mfma_f32_16x16x32_bf16(aF[m], bF[n], acc[m][n], 0, 0, 0);
        }
    }

    // fused layer 2: this wave's 64 hidden cols -> 5 partials per row
    float b1c[4], w2c[4][5];
#pragma unroll
    for (int n = 0; n < 4; ++n) {
        int col = wv * 64 + n * 16 + c15;
        b1c[n] = b1[col];
#pragma unroll
        for (int j = 0; j < 5; ++j) w2c[n][j] = W2[col * 5 + j];
    }
#pragma unroll
    for (int m = 0; m < 4; ++m) {
#pragma unroll
        for (int reg = 0; reg < 4; ++reg) {
            float s[5] = {0.f, 0.f, 0.f, 0.f, 0.f};
#pragma unroll
            for (int n = 0; n < 4; ++n) {
                float p = fmaxf(acc[m][n][reg] + b1c[n], 0.f);
#pragma unroll
                for (int j = 0; j < 5; ++j) s[j] += p * w2c[n][j];
            }
#pragma unroll
            for (int off = 1; off < 16; off <<= 1)
#pragma unroll
                for (int j = 0; j < 5; ++j) s[j] += __shfl_xor(s[j], off);
            if (c15 == 0) {
                int rl = m * 16 + kq * 4 + reg;
#pragma unroll
                for (int j = 0; j < 5; ++j) atomicAdd(&obuf[rl][j], s[j]);
            }
        }
    }
    __syncthreads();
    {
        int r = tid >> 3, j = tid & 7;
        if (j < 5) {
            int row = b0 + r;
            if (row < NB) outB[(size_t)row * 5 + j] = obuf[r][j] + b2[j];
        }
    }
}

// ---------------------------------------------------------------------------
// uni: logits = relu(ha @ W1 + b1) @ W2 + b2. BM=64 atoms, N=512, K=256.
// Same template as bond; A rows are linear (no gather).
// ---------------------------------------------------------------------------
__global__ __launch_bounds__(512, 4) void uni_kernel(
    const unsigned short* __restrict__ haB, const unsigned short* __restrict__ uW1T,
    const float* __restrict__ b1, const float* __restrict__ W2,
    const float* __restrict__ b2, float* __restrict__ outU, int NA)
{
    __shared__ __align__(16) unsigned short As[64 * 64];
    __shared__ __align__(16) unsigned short Bs[512 * 64];
    __shared__ float obuf[64];

    const int tid = threadIdx.x;
    const int wv = tid >> 6, lane = tid & 63;
    const int c15 = lane & 15, kq = lane >> 4;
    const int xm3 = (c15 & 7) << 3;
    const int a0 = blockIdx.x * 64;

    if (tid < 64) obuf[tid] = 0.f;

    const int rA = wv * 8 + (lane >> 3);
    const int srcswz = ((lane & 7) ^ ((lane >> 3) & 7)) << 3;
    int r0 = a0 + rA; if (r0 >= NA) r0 = NA - 1;

    f32x4 acc[4][4];
#pragma unroll
    for (int m = 0; m < 4; ++m)
#pragma unroll
        for (int n = 0; n < 4; ++n) acc[m][n] = (f32x4){0.f, 0.f, 0.f, 0.f};

    for (int ks = 0; ks < 4; ++ks) {
        __syncthreads();
        const unsigned short* bt = uW1T + ks * 32768;
#pragma unroll
        for (int j = 0; j < 8; ++j) {
            GLOAD16(bt + (size_t)((j * 8 + wv) * 512) + lane * 8,
                    Bs + (j * 8 + wv) * 512);
        }
        GLOAD16(haB + (size_t)r0 * 256 + ks * 64 + srcswz, As + wv * 512);
        __syncthreads();
#pragma unroll
        for (int kk = 0; kk < 2; ++kk) {
            bf16x8 aF[4], bF[4];
#pragma unroll
            for (int m = 0; m < 4; ++m)
                aF[m] = *(const bf16x8*)&As[(m * 16 + c15) * 64 + ((kk * 32 + kq * 8) ^ xm3)];
#pragma unroll
            for (int n = 0; n < 4; ++n)
                bF[n] = *(const bf16x8*)&Bs[(wv * 64 + n * 16 + c15) * 64 + ((kk * 32 + kq * 8) ^ xm3)];
#pragma unroll
            for (int m = 0; m < 4; ++m)
#pragma unroll
                for (int n = 0; n < 4; ++n)
                    acc[m][n] = __builtin_amdgcn_mfma_f32_16x16x32_bf16(aF[m], bF[n], acc[m][n], 0, 0, 0);
        }
    }

    float b1c[4], w2c[4];
#pragma unroll
    for (int n = 0; n < 4; ++n) {
        int col = wv * 64 + n * 16 + c15;
        b1c[n] = b1[col];
        w2c[n] = W2[col];
    }
#pragma unroll
    for (int m = 0; m < 4; ++m) {
#pragma unroll
        for (int reg = 0; reg < 4; ++reg) {
            float s = 0.f;
#pragma unroll
            for (int n = 0; n < 4; ++n)
                s += fmaxf(acc[m][n][reg] + b1c[n], 0.f) * w2c[n];
#pragma unroll
            for (int off = 1; off < 16; off <<= 1) s += __shfl_xor(s, off);
            if (c15 == 0) atomicAdd(&obuf[m * 16 + kq * 4 + reg], s);
        }
    }
    __syncthreads();
    if (tid < 64) {
        int row = a0 + tid;
        if (row < NA) outU[row] = obuf[tid] + b2[0];
    }
}

// ---------------------------------------------------------------------------
// done_logits: 4 molecules per block (W1 streamed once per 4 mols), fp32
// ---------------------------------------------------------------------------
__global__ __launch_bounds__(256) void done_kernel(
    const float* __restrict__ hm, const float* __restrict__ W1,
    const float* __restrict__ b1, const float* __restrict__ W2,
    const float* __restrict__ b2, float* __restrict__ outD, int NM)
{
    __shared__ float rsh[4][256];
    __shared__ float red[4][4];
    const int tid = threadIdx.x;
    const int wv = tid >> 6, lane = tid & 63;
    const int mol0 = blockIdx.x * 4;
#pragma unroll
    for (int q = 0; q < 4; ++q)
        rsh[q][tid] = (mol0 + q < NM) ? hm[(size_t)(mol0 + q) * 256 + tid] : 0.f;
    __syncthreads();
    float h[4][2];
#pragma unroll
    for (int q = 0; q < 4; ++q) { h[q][0] = 0.f; h[q][1] = 0.f; }
    for (int k = 0; k < 256; ++k) {
        float w0 = W1[k * 512 + tid];
        float w1 = W1[k * 512 + tid + 256];
#pragma unroll
        for (int q = 0; q < 4; ++q) {
            h[q][0] += rsh[q][k] * w0;
            h[q][1] += rsh[q][k] * w1;
        }
    }
    float bb0 = b1[tid], bb1v = b1[tid + 256];
    float ww0 = W2[tid], ww1 = W2[tid + 256];
#pragma unroll
    for (int q = 0; q < 4; ++q) {
        float p = fmaxf(h[q][0] + bb0, 0.f) * ww0 + fmaxf(h[q][1] + bb1v, 0.f) * ww1;
#pragma unroll
        for (int off = 1; off < 64; off <<= 1) p += __shfl_xor(p, off);
        if (lane == 0) red[q][wv] = p;
    }
    __syncthreads();
    if (tid < 4 && mol0 + tid < NM)
        outD[mol0 + tid] = red[tid][0] + red[tid][1] + red[tid][2] + red[tid][3] + b2[0];
}

// ---------------------------------------------------------------------------
extern "C" void kernel_launch(void* const* d_in, const int* in_sizes, int n_in,
                              void* d_out, int out_size, void* d_ws, size_t ws_size,
                              hipStream_t stream)
{
    const float* c_atom  = (const float*)d_in[0];
    const float* ha_prev = (const float*)d_in[1];
    const float* W_vv    = (const float*)d_in[2];
    const float* W_vc    = (const float*)d_in[3];
    const float* bW1     = (const float*)d_in[4];
    const float* bb1     = (const float*)d_in[5];
    const float* bW2     = (const float*)d_in[6];
    const float* bb2     = (const float*)d_in[7];
    const float* uW1     = (const float*)d_in[8];
    const float* ub1     = (const float*)d_in[9];
    const float* uW2     = (const float*)d_in[10];
    const float* ub2     = (const float*)d_in[11];
    const float* dW1     = (const float*)d_in[12];
    const float* db1     = (const float*)d_in[13];
    const float* dW2     = (const float*)d_in[14];
    const float* db2     = (const float*)d_in[15];
    const int* mol_id    = (const int*)d_in[16];
    const int* bidx      = (const int*)d_in[17];

    const int H = 256, BS = 5;
    const int NA = in_sizes[0] / H;
    const int NB = in_sizes[17] / 2;
    const int NM = out_size - NB * BS - NA;

    float* out  = (float*)d_out;
    float* outB = out;
    float* outU = out + (size_t)NB * BS;
    float* outD = outU + NA;

    char* ws = (char*)d_ws;
    size_t off = 0;
    unsigned short* haB = (unsigned short*)(ws + off);
    off += (size_t)NA * H * 2;            off = (off + 255) & ~(size_t)255;
    float* hm = (float*)(ws + off);
    off += (size_t)NM * H * 4;            off = (off + 255) & ~(size_t)255;
    unsigned short* WcT = (unsigned short*)(ws + off);
    off += (size_t)131072 * 2;            off = (off + 255) & ~(size_t)255;
    unsigned short* bW1T = (unsigned short*)(ws + off);
    off += (size_t)262144 * 2;            off = (off + 255) & ~(size_t)255;
    unsigned short* uW1T = (unsigned short*)(ws + off);

    hipMemsetAsync(hm, 0, (size_t)NM * H * 4, stream);
    conv_weights<<<2048, 256, 0, stream>>>(W_vv, W_vc, bW1, uW1, WcT, bW1T, uW1T);
    ha_kernel<<<(NA + 127) / 128, 512, 0, stream>>>(ha_prev, c_atom, WcT, mol_id, haB, hm, NA);
    bond_kernel<<<(NB + 63) / 64, 512, 0, stream>>>(haB, bidx, bW1T, bb1, bW2, bb2, outB, NB);
    uni_kernel<<<(NA + 63) / 64, 512, 0, stream>>>(haB, uW1T, ub1, uW2, ub2, outU, NA);
    done_kernel<<<(NM + 3) / 4, 256, 0, stream>>>(hm, dW1, db1, dW2, db2, outD, NM);
}

// Round 4
// 633.253 us; speedup vs baseline: 2.5721x; 1.2639x over previous
//
#include <hip/hip_runtime.h>
#include <hip/hip_bf16.h>

typedef __attribute__((ext_vector_type(8))) short bf16x8;
typedef __attribute__((ext_vector_type(4))) float f32x4;

static __device__ __forceinline__ unsigned short f2bf(float f) {
    union { float f; unsigned u; } v; v.f = f;
    unsigned r = v.u + 0x7fffu + ((v.u >> 16) & 1u);
    return (unsigned short)(r >> 16);
}

#define GLOAD16(g, l) __builtin_amdgcn_global_load_lds( \
    (const __attribute__((address_space(1))) void*)(g), \
    (__attribute__((address_space(3))) void*)(l), 16, 0, 0)

// ---------------------------------------------------------------------------
// Weight conversion: fp32 -> bf16, plane-major for direct global->VGPR frag
// loads: dst[((k>>3)*N + n)*8 + (k&7)]. A wave's 64 lanes reading frag n at
// (ks,kk) touch 4 planes x 256B contiguous -> coalesced L2 hits.
// WcT: N=256,K=512 (vv rows then vc rows); bW1T: N=512,K=512; uW1T: N=512,K=256
// ---------------------------------------------------------------------------
__global__ __launch_bounds__(256) void conv_weights(
    const float* __restrict__ Wvv, const float* __restrict__ Wvc,
    const float* __restrict__ bW1, const float* __restrict__ uW1,
    unsigned short* __restrict__ WcT, unsigned short* __restrict__ bW1T,
    unsigned short* __restrict__ uW1T)
{
    int idx = blockIdx.x * 256 + threadIdx.x;
    if (idx < 131072) {                       // WcT
        int n = idx & 255, k = idx >> 8;
        float s = (k < 256) ? Wvv[k * 256 + n] : Wvc[(k - 256) * 256 + n];
        WcT[((k >> 3) * 256 + n) * 8 + (k & 7)] = f2bf(s);
    } else if (idx < 131072 + 262144) {       // bW1T
        int t = idx - 131072;
        int n = t & 511, k = t >> 9;
        bW1T[((k >> 3) * 512 + n) * 8 + (k & 7)] = f2bf(bW1[k * 512 + n]);
    } else if (idx < 131072 + 262144 + 131072) { // uW1T
        int t = idx - 393216;
        int n = t & 511, k = t >> 9;
        uW1T[((k >> 3) * 512 + n) * 8 + (k & 7)] = f2bf(uW1[k * 512 + n]);
    }
}

// ---------------------------------------------------------------------------
// ha = relu(ha_prev @ W_vv + c_atom @ W_vc); ha[0]=0
// BM=128, N=256, K=512. 8 waves (2x4), 64x64 each. B direct from L2 (no LDS).
// A: fp32->bf16 reg-staged, LDS double-buffered, 1 barrier/step.
// ---------------------------------------------------------------------------
__global__ __launch_bounds__(512, 4) void ha_kernel(
    const float* __restrict__ ha_prev, const float* __restrict__ c_atom,
    const unsigned short* __restrict__ WcT, const int* __restrict__ mol_id,
    unsigned short* __restrict__ haB, float* __restrict__ hm, int NA)
{
    __shared__ __align__(16) unsigned short As[2][128 * 64];

    const int tid = threadIdx.x;
    const int wv = tid >> 6, lane = tid & 63;
    const int wr = wv >> 2, wc = wv & 3;
    const int c15 = lane & 15, kq = lane >> 4;
    const int xm3 = (c15 & 7) << 3;
    const int m0 = blockIdx.x * 128;

    const int cr0 = tid >> 3, chc = tid & 7;           // staging: chunk -> row/half
    const int cr1 = (512 + tid) >> 3;
    int row0 = m0 + cr0; if (row0 >= NA) row0 = NA - 1;
    int row1 = m0 + cr1; if (row1 >= NA) row1 = NA - 1;

    f32x4 v00, v01, v10, v11;
    #define HA_LOAD(ks) { \
        const float* src = ((ks) < 4) ? ha_prev : c_atom; \
        const int kb = ((ks) & 3) * 64 + chc * 8; \
        const float* s0 = src + (size_t)row0 * 256 + kb; \
        const float* s1 = src + (size_t)row1 * 256 + kb; \
        v00 = *(const f32x4*)s0; v01 = *(const f32x4*)(s0 + 4); \
        v10 = *(const f32x4*)s1; v11 = *(const f32x4*)(s1 + 4); }
    #define HA_WRITE(buf) { \
        bf16x8 p0, p1; \
        p0[0]=(short)f2bf(v00[0]); p0[1]=(short)f2bf(v00[1]); p0[2]=(short)f2bf(v00[2]); p0[3]=(short)f2bf(v00[3]); \
        p0[4]=(short)f2bf(v01[0]); p0[5]=(short)f2bf(v01[1]); p0[6]=(short)f2bf(v01[2]); p0[7]=(short)f2bf(v01[3]); \
        p1[0]=(short)f2bf(v10[0]); p1[1]=(short)f2bf(v10[1]); p1[2]=(short)f2bf(v10[2]); p1[3]=(short)f2bf(v10[3]); \
        p1[4]=(short)f2bf(v11[0]); p1[5]=(short)f2bf(v11[1]); p1[6]=(short)f2bf(v11[2]); p1[7]=(short)f2bf(v11[3]); \
        *(bf16x8*)&As[buf][cr0 * 64 + ((chc * 8) ^ ((cr0 & 7) << 3))] = p0; \
        *(bf16x8*)&As[buf][cr1 * 64 + ((chc * 8) ^ ((cr1 & 7) << 3))] = p1; }

    f32x4 acc[4][4];
#pragma unroll
    for (int m = 0; m < 4; ++m)
#pragma unroll
        for (int n = 0; n < 4; ++n) acc[m][n] = (f32x4){0.f, 0.f, 0.f, 0.f};

    HA_LOAD(0); HA_WRITE(0);
    __syncthreads();

    for (int ks = 0; ks < 8; ++ks) {
        if (ks < 7) HA_LOAD(ks + 1);
        const int buf = ks & 1;
#pragma unroll
        for (int kk = 0; kk < 2; ++kk) {
            bf16x8 aF[4], bF[4];
            const int plane = ks * 8 + kk * 4 + kq;
#pragma unroll
            for (int n = 0; n < 4; ++n)
                bF[n] = *(const bf16x8*)(WcT + ((size_t)plane * 256 + wc * 64 + n * 16 + c15) * 8);
#pragma unroll
            for (int m = 0; m < 4; ++m)
                aF[m] = *(const bf16x8*)&As[buf][(wr * 64 + m * 16 + c15) * 64 + ((kk * 32 + kq * 8) ^ xm3)];
#pragma unroll
            for (int m = 0; m < 4; ++m)
#pragma unroll
                for (int n = 0; n < 4; ++n)
                    acc[m][n] = __builtin_amdgcn_mfma_f32_16x16x32_bf16(aF[m], bF[n], acc[m][n], 0, 0, 0);
        }
        if (ks < 7) HA_WRITE((ks + 1) & 1);
        __syncthreads();
    }

#pragma unroll
    for (int m = 0; m < 4; ++m) {
#pragma unroll
        for (int reg = 0; reg < 4; ++reg) {
            int row = m0 + wr * 64 + m * 16 + kq * 4 + reg;
            if (row >= NA) continue;
            bool z = (row == 0);
            int mol = z ? 0 : mol_id[row];
#pragma unroll
            for (int n = 0; n < 4; ++n) {
                int col = wc * 64 + n * 16 + c15;
                float v = fmaxf(acc[m][n][reg], 0.f);
                if (z) v = 0.f;
                haB[(size_t)row * 256 + col] = f2bf(v);
                if (!z) atomicAdd(&hm[mol * 256 + col], v);
            }
        }
    }
}

// ---------------------------------------------------------------------------
// bond: logits = relu([ha[b0]|ha[b1]] @ W1 + b1) @ W2 + b2, fully fused.
// BM=64 bonds, N=512, K=512. Full-K A resident in LDS (64 KB), staged once
// (one GLOAD16 per bond: 512B per endpoint, chunk-permuted src for swizzle).
// B direct global->VGPR from L2. NO barriers in the K loop.
// ---------------------------------------------------------------------------
__global__ __launch_bounds__(512, 4) void bond_kernel(
    const unsigned short* __restrict__ haB, const int* __restrict__ bidx,
    const unsigned short* __restrict__ bW1T, const float* __restrict__ b1,
    const float* __restrict__ W2, const float* __restrict__ b2,
    float* __restrict__ outB, int NB)
{
    __shared__ __align__(16) unsigned short As[64 * 512];   // 64 KB: [bond][ep][256]
    __shared__ float obuf[64][5];

    const int tid = threadIdx.x;
    const int wv = tid >> 6, lane = tid & 63;
    const int c15 = lane & 15, kq = lane >> 4;
    const int b0 = blockIdx.x * 64;

    if (tid < 320) ((float*)obuf)[tid] = 0.f;

    // stage A: wave wv stages bonds wv*8 .. wv*8+7 (1 KB each, one GLOAD16)
    const int ep = lane >> 5, sl = lane & 31;
    int eidx[8];
#pragma unroll
    for (int i = 0; i < 8; ++i) {
        int gb = b0 + wv * 8 + i; if (gb >= NB) gb = 0;
        eidx[i] = bidx[gb * 2 + ep];
    }
#pragma unroll
    for (int i = 0; i < 8; ++i) {
        int r = wv * 8 + i;
        GLOAD16(haB + (size_t)eidx[i] * 256 + (size_t)((sl ^ (r & 7)) * 8),
                As + r * 512);
    }
    __syncthreads();

    f32x4 acc[4][4];
#pragma unroll
    for (int m = 0; m < 4; ++m)
#pragma unroll
        for (int n = 0; n < 4; ++n) acc[m][n] = (f32x4){0.f, 0.f, 0.f, 0.f};

    for (int ks = 0; ks < 8; ++ks) {
#pragma unroll
        for (int kk = 0; kk < 2; ++kk) {
            bf16x8 aF[4], bF[4];
            const int plane = ks * 8 + kk * 4 + kq;
#pragma unroll
            for (int n = 0; n < 4; ++n)
                bF[n] = *(const bf16x8*)(bW1T + ((size_t)plane * 512 + wv * 64 + n * 16 + c15) * 8);
#pragma unroll
            for (int m = 0; m < 4; ++m) {
                int r = m * 16 + c15;
                int ch = (((ks & 3) * 8 + kk * 4 + kq) ^ (r & 7));
                aF[m] = *(const bf16x8*)&As[r * 512 + (ks >> 2) * 256 + ch * 8];
            }
#pragma unroll
            for (int m = 0; m < 4; ++m)
#pragma unroll
                for (int n = 0; n < 4; ++n)
                    acc[m][n] = __builtin_amdgcn_mfma_f32_16x16x32_bf16(aF[m], bF[n], acc[m][n], 0, 0, 0);
        }
    }

    // fused layer 2: this wave's 64 hidden cols -> 5 partials per row
    float b1c[4], w2c[4][5];
#pragma unroll
    for (int n = 0; n < 4; ++n) {
        int col = wv * 64 + n * 16 + c15;
        b1c[n] = b1[col];
#pragma unroll
        for (int j = 0; j < 5; ++j) w2c[n][j] = W2[col * 5 + j];
    }
#pragma unroll
    for (int m = 0; m < 4; ++m) {
#pragma unroll
        for (int reg = 0; reg < 4; ++reg) {
            float s[5] = {0.f, 0.f, 0.f, 0.f, 0.f};
#pragma unroll
            for (int n = 0; n < 4; ++n) {
                float p = fmaxf(acc[m][n][reg] + b1c[n], 0.f);
#pragma unroll
                for (int j = 0; j < 5; ++j) s[j] += p * w2c[n][j];
            }
#pragma unroll
            for (int off = 1; off < 16; off <<= 1)
#pragma unroll
                for (int j = 0; j < 5; ++j) s[j] += __shfl_xor(s[j], off);
            if (c15 == 0) {
                int rl = m * 16 + kq * 4 + reg;
#pragma unroll
                for (int j = 0; j < 5; ++j) atomicAdd(&obuf[rl][j], s[j]);
            }
        }
    }
    __syncthreads();
    {
        int r = tid >> 3, j = tid & 7;
        if (j < 5) {
            int row = b0 + r;
            if (row < NB) outB[(size_t)row * 5 + j] = obuf[r][j] + b2[j];
        }
    }
}

// ---------------------------------------------------------------------------
// uni: logits = relu(ha @ W1 + b1) @ W2 + b2. BM=64 atoms, N=512, K=256.
// Full-K A resident (32 KB), B direct from L2, no barriers in K loop.
// ---------------------------------------------------------------------------
__global__ __launch_bounds__(512, 4) void uni_kernel(
    const unsigned short* __restrict__ haB, const unsigned short* __restrict__ uW1T,
    const float* __restrict__ b1, const float* __restrict__ W2,
    const float* __restrict__ b2, float* __restrict__ outU, int NA)
{
    __shared__ __align__(16) unsigned short As[64 * 256];   // 32 KB
    __shared__ float obuf[64];

    const int tid = threadIdx.x;
    const int wv = tid >> 6, lane = tid & 63;
    const int c15 = lane & 15, kq = lane >> 4;
    const int a0 = blockIdx.x * 64;

    if (tid < 64) obuf[tid] = 0.f;

    // stage A: wave wv stages rows wv*8 .. wv*8+7 (512B each; GLOAD16 = 2 rows)
    const int rr = lane >> 5, sl = lane & 31;
#pragma unroll
    for (int i = 0; i < 4; ++i) {
        int r = wv * 8 + i * 2 + rr;
        int ga = a0 + r; if (ga >= NA) ga = NA - 1;
        GLOAD16(haB + (size_t)ga * 256 + (size_t)((sl ^ (r & 7)) * 8),
                As + (wv * 8 + i * 2) * 256);
    }
    __syncthreads();

    f32x4 acc[4][4];
#pragma unroll
    for (int m = 0; m < 4; ++m)
#pragma unroll
        for (int n = 0; n < 4; ++n) acc[m][n] = (f32x4){0.f, 0.f, 0.f, 0.f};

    for (int ks = 0; ks < 4; ++ks) {
#pragma unroll
        for (int kk = 0; kk < 2; ++kk) {
            bf16x8 aF[4], bF[4];
            const int plane = ks * 8 + kk * 4 + kq;
#pragma unroll
            for (int n = 0; n < 4; ++n)
                bF[n] = *(const bf16x8*)(uW1T + ((size_t)plane * 512 + wv * 64 + n * 16 + c15) * 8);
#pragma unroll
            for (int m = 0; m < 4; ++m) {
                int r = m * 16 + c15;
                int ch = ((ks * 8 + kk * 4 + kq) ^ (r & 7));
                aF[m] = *(const bf16x8*)&As[r * 256 + ch * 8];
            }
#pragma unroll
            for (int m = 0; m < 4; ++m)
#pragma unroll
                for (int n = 0; n < 4; ++n)
                    acc[m][n] = __builtin_amdgcn_mfma_f32_16x16x32_bf16(aF[m], bF[n], acc[m][n], 0, 0, 0);
        }
    }

    float b1c[4], w2c[4];
#pragma unroll
    for (int n = 0; n < 4; ++n) {
        int col = wv * 64 + n * 16 + c15;
        b1c[n] = b1[col];
        w2c[n] = W2[col];
    }
#pragma unroll
    for (int m = 0; m < 4; ++m) {
#pragma unroll
        for (int reg = 0; reg < 4; ++reg) {
            float s = 0.f;
#pragma unroll
            for (int n = 0; n < 4; ++n)
                s += fmaxf(acc[m][n][reg] + b1c[n], 0.f) * w2c[n];
#pragma unroll
            for (int off = 1; off < 16; off <<= 1) s += __shfl_xor(s, off);
            if (c15 == 0) atomicAdd(&obuf[m * 16 + kq * 4 + reg], s);
        }
    }
    __syncthreads();
    if (tid < 64) {
        int row = a0 + tid;
        if (row < NA) outU[row] = obuf[tid] + b2[0];
    }
}

// ---------------------------------------------------------------------------
// done_logits: 4 molecules per block (W1 streamed once per 4 mols), fp32
// ---------------------------------------------------------------------------
__global__ __launch_bounds__(256) void done_kernel(
    const float* __restrict__ hm, const float* __restrict__ W1,
    const float* __restrict__ b1, const float* __restrict__ W2,
    const float* __restrict__ b2, float* __restrict__ outD, int NM)
{
    __shared__ float rsh[4][256];
    __shared__ float red[4][4];
    const int tid = threadIdx.x;
    const int wv = tid >> 6, lane = tid & 63;
    const int mol0 = blockIdx.x * 4;
#pragma unroll
    for (int q = 0; q < 4; ++q)
        rsh[q][tid] = (mol0 + q < NM) ? hm[(size_t)(mol0 + q) * 256 + tid] : 0.f;
    __syncthreads();
    float h[4][2];
#pragma unroll
    for (int q = 0; q < 4; ++q) { h[q][0] = 0.f; h[q][1] = 0.f; }
    for (int k = 0; k < 256; ++k) {
        float w0 = W1[k * 512 + tid];
        float w1 = W1[k * 512 + tid + 256];
#pragma unroll
        for (int q = 0; q < 4; ++q) {
            h[q][0] += rsh[q][k] * w0;
            h[q][1] += rsh[q][k] * w1;
        }
    }
    float bb0 = b1[tid], bb1v = b1[tid + 256];
    float ww0 = W2[tid], ww1 = W2[tid + 256];
#pragma unroll
    for (int q = 0; q < 4; ++q) {
        float p = fmaxf(h[q][0] + bb0, 0.f) * ww0 + fmaxf(h[q][1] + bb1v, 0.f) * ww1;
#pragma unroll
        for (int off = 1; off < 64; off <<= 1) p += __shfl_xor(p, off);
        if (lane == 0) red[q][wv] = p;
    }
    __syncthreads();
    if (tid < 4 && mol0 + tid < NM)
        outD[mol0 + tid] = red[tid][0] + red[tid][1] + red[tid][2] + red[tid][3] + b2[0];
}

// ---------------------------------------------------------------------------
extern "C" void kernel_launch(void* const* d_in, const int* in_sizes, int n_in,
                              void* d_out, int out_size, void* d_ws, size_t ws_size,
                              hipStream_t stream)
{
    const float* c_atom  = (const float*)d_in[0];
    const float* ha_prev = (const float*)d_in[1];
    const float* W_vv    = (const float*)d_in[2];
    const float* W_vc    = (const float*)d_in[3];
    const float* bW1     = (const float*)d_in[4];
    const float* bb1     = (const float*)d_in[5];
    const float* bW2     = (const float*)d_in[6];
    const float* bb2     = (const float*)d_in[7];
    const float* uW1     = (const float*)d_in[8];
    const float* ub1     = (const float*)d_in[9];
    const float* uW2     = (const float*)d_in[10];
    const float* ub2     = (const float*)d_in[11];
    const float* dW1     = (const float*)d_in[12];
    const float* db1     = (const float*)d_in[13];
    const float* dW2     = (const float*)d_in[14];
    const float* db2     = (const float*)d_in[15];
    const int* mol_id    = (const int*)d_in[16];
    const int* bidx      = (const int*)d_in[17];

    const int H = 256, BS = 5;
    const int NA = in_sizes[0] / H;
    const int NB = in_sizes[17] / 2;
    const int NM = out_size - NB * BS - NA;

    float* out  = (float*)d_out;
    float* outB = out;
    float* outU = out + (size_t)NB * BS;
    float* outD = outU + NA;

    char* ws = (char*)d_ws;
    size_t off = 0;
    unsigned short* haB = (unsigned short*)(ws + off);
    off += (size_t)NA * H * 2;            off = (off + 255) & ~(size_t)255;
    float* hm = (float*)(ws + off);
    off += (size_t)NM * H * 4;            off = (off + 255) & ~(size_t)255;
    unsigned short* WcT = (unsigned short*)(ws + off);
    off += (size_t)131072 * 2;            off = (off + 255) & ~(size_t)255;
    unsigned short* bW1T = (unsigned short*)(ws + off);
    off += (size_t)262144 * 2;            off = (off + 255) & ~(size_t)255;
    unsigned short* uW1T = (unsigned short*)(ws + off);

    hipMemsetAsync(hm, 0, (size_t)NM * H * 4, stream);
    conv_weights<<<2048, 256, 0, stream>>>(W_vv, W_vc, bW1, uW1, WcT, bW1T, uW1T);
    ha_kernel<<<(NA + 127) / 128, 512, 0, stream>>>(ha_prev, c_atom, WcT, mol_id, haB, hm, NA);
    bond_kernel<<<(NB + 63) / 64, 512, 0, stream>>>(haB, bidx, bW1T, bb1, bW2, bb2, outB, NB);
    uni_kernel<<<(NA + 63) / 64, 512, 0, stream>>>(haB, uW1T, ub1, uW2, ub2, outU, NA);
    done_kernel<<<(NM + 3) / 4, 256, 0, stream>>>(hm, dW1, db1, dW2, db2, outD, NM);
}